// Round 4
// baseline (364.121 us; speedup 1.0000x reference)
//
#include <hip/hip_runtime.h>

#define NPIL 12000
#define NPTS 100
#define CIN 9
#define COUT 32

__launch_bounds__(256, 4)
__global__ void pfn_kernel(const float* __restrict__ px, const float* __restrict__ py,
                           const float* __restrict__ pz, const float* __restrict__ pi,
                           const int*   __restrict__ nvox,
                           const float* __restrict__ xs, const float* __restrict__ ys,
                           const float* __restrict__ mk,
                           const float* __restrict__ W,  const float* __restrict__ gma,
                           const float* __restrict__ bta, const float* __restrict__ bmean,
                           const float* __restrict__ bvar,
                           float* __restrict__ out) {
    __shared__ float lin8[NPTS][8];   // [n][x,y,z,i,xs,ys,m,pad] — 3.2 KB
    __shared__ float lmean[3];
    __shared__ int   lmax[COUT];

    const int p = blockIdx.x;
    const int t = threadIdx.x;
    const float fnv = (float)nvox[p];     // hoisted: off the inter-barrier critical path

    // ---- stage: threads 0..99 load their point's 7 scalars (coalesced) ----
    if (t < NPTS) {
        const size_t o = (size_t)p * NPTS + t;
        lin8[t][0] = px[o]; lin8[t][1] = py[o]; lin8[t][2] = pz[o]; lin8[t][3] = pi[o];
        lin8[t][4] = xs[o]; lin8[t][5] = ys[o]; lin8[t][6] = mk[o];
    }
    if (t >= 224) lmax[t - 224] = 0;      // lanes idle in staging zero the max slots
    __syncthreads();

    // ---- unmasked x/y/z sums over all 100 slots, / num_voxels ----
    if (t < 96) {
        int c = t >> 5, j = t & 31;
        float v = lin8[j][c] + lin8[j + 32][c] + lin8[j + 64][c];
        if (j < 4) v += lin8[j + 96][c];
        v += __shfl_xor(v, 16);
        v += __shfl_xor(v, 8);
        v += __shfl_xor(v, 4);
        v += __shfl_xor(v, 2);
        v += __shfl_xor(v, 1);
        if (j == 0) lmean[c] = v / fnv;
    }

    // ---- per-thread fixed output channel u; fold BN into weights ----
    const int u = t & 31;
    const float s  = rsqrtf(bvar[u] + 1e-3f) * gma[u];
    const float b  = bta[u] - bmean[u] * s;
    const float w0 = W[u * CIN + 0] * s, w1 = W[u * CIN + 1] * s, w2 = W[u * CIN + 2] * s;
    const float w3 = W[u * CIN + 3] * s, w4 = W[u * CIN + 4] * s, w5 = W[u * CIN + 5] * s;
    const float w6 = W[u * CIN + 6] * s, w7 = W[u * CIN + 7] * s, w8 = W[u * CIN + 8] * s;
    __syncthreads();

    const float mx = lmean[0], my = lmean[1], mz = lmean[2];
    float* outp = out + (size_t)p * (NPTS * 64);
    float vmax = 0.f;
    for (int n = (t >> 5); n < NPTS; n += 8) {
        float4 a = *(const float4*)&lin8[n][0];   // x,y,z,i — uniform addr per half-wave
        float4 c4 = *(const float4*)&lin8[n][4];  // xs,ys,m,pad
        float dot = a.x * w0 + a.y * w1 + a.z * w2 + a.w * w3
                  + (a.x - mx) * w4 + (a.y - my) * w5 + (a.z - mz) * w6
                  + (a.x - c4.x) * w7 + (a.y - c4.y) * w8;
        float v = fmaxf(fmaf(c4.z, dot, b), 0.f);
        outp[n * 64 + u] = v;                     // direct store: 128B contiguous / half-wave
        vmax = fmaxf(vmax, v);
    }
    atomicMax(&lmax[u], __float_as_int(vmax));    // bits monotonic for floats >= 0
    __syncthreads();

    // ---- upper halves: out[p][n][32..63] = max (8 float4 rows, 1KB/wave-instr) ----
    const float4* lmax4 = (const float4*)lmax;
    for (int idx = t; idx < NPTS * 8; idx += 256) {
        int n = idx >> 3, q = idx & 7;
        ((float4*)(outp + n * 64 + 32))[q] = lmax4[q];
    }
}

extern "C" void kernel_launch(void* const* d_in, const int* in_sizes, int n_in,
                              void* d_out, int out_size, void* d_ws, size_t ws_size,
                              hipStream_t stream) {
    const float* px  = (const float*)d_in[0];
    const float* py  = (const float*)d_in[1];
    const float* pz  = (const float*)d_in[2];
    const float* pi  = (const float*)d_in[3];
    const int*   nv  = (const int*)  d_in[4];
    const float* xs  = (const float*)d_in[5];
    const float* ys  = (const float*)d_in[6];
    const float* mk  = (const float*)d_in[7];
    const float* W   = (const float*)d_in[8];
    const float* gma = (const float*)d_in[9];
    const float* bta = (const float*)d_in[10];
    const float* bmn = (const float*)d_in[11];
    const float* bvr = (const float*)d_in[12];
    float* out = (float*)d_out;

    pfn_kernel<<<dim3(NPIL), dim3(256), 0, stream>>>(
        px, py, pz, pi, nv, xs, ys, mk, W, gma, bta, bmn, bvr, out);
}